// Round 6
// baseline (673.641 us; speedup 1.0000x reference)
//
#include <hip/hip_runtime.h>
#include <stdint.h>

// Self-attention, SEQ=8192, D=768, single head.
//   K0a: x fp32->bf16; K0b: Wq/Wk/Wv fp32->bf16 (z-fused)
//   K1a: Q,K projections z-fused (MODE 0); K1b: Vt = Wv x^T (MODE 0)
//   K2 : P' = exp(Q K^T) bf16 + atomic row sums (MODE 1)
//   K3 : out += (P'_chunk V)/rowsum, split-K x4, fp32 atomicAdd (MODE 2)
//
// R16: 256^2 8-phase counted-vmcnt engine (m201-class structure, plain HIP).
// R8/R10/R15 all plateau at 620-660 TF: at 128^2/4-wave, LDS traffic is
// ~32 B/KFLOP (cap ~65% MfmaUtil at 128 B/cyc LDS) and the per-K-step
// vmcnt(0)+barrier drain dominates (m233). Fix per T3/T4: 256^2 tile,
// 8 waves (2Mx4N), per-wave C 128x64, BK=64, LDS dbuf 128 KB, 8 phases
// per 2 K-tiles, vmcnt(4) ONLY at phases 4/8 (loads span barriers).
// Region-liveness proof (phase -> LDS ds_read): A0@ph1, B0@ph1, B1@ph2,
// A1@ph3 (regs held across phases: a-half 2 phases, b0 4 phases, b1 2).
// Stage slots (one 16KB half-tile per phase, target dead + barrier-separated):
//   ph1:(j+1).B0->d1  ph2:(j+1).A1->d1  ph3:(j+2).A0->d0  ph4:(j+2).B1->d0
//   ph5:(j+2).B0->d0  ph6:(j+2).A1->d0  ph7:(j+3).A0->d1  ph8:(j+3).B1->d1
// vmcnt(4) at ph4 end leaves ph3,4 issues in flight -> tile j+1 resident
// for ph5; at ph8 leaves ph7,8 -> tile j+2 resident for next ph1. Last
// iteration: no stages for j+2/j+3, single vmcnt(0) at ph4.
// Kept verified pieces: 32x32x16 MFMA maps (m74/m101), 3-bit XOR swizzle
// (read-side conflict-free, R15; residual 1.26e7 = DMA write floor),
// linear gload_lds dest (m104) + source-column swizzle (m173).
// T5 setprio around MFMA (m218b: +21-25% on 8-phase).

#define SEQ    8192
#define DMODEL 768
#define KSPLIT 4

typedef short bf16x8 __attribute__((ext_vector_type(8)));
typedef float f32x16 __attribute__((ext_vector_type(16)));

__device__ __forceinline__ unsigned short f2bf(float f) {
  union { float f; unsigned int u; } v; v.f = f;
  unsigned int u = v.u;
  u += 0x7FFFu + ((u >> 16) & 1u);   // round-to-nearest-even
  return (unsigned short)(u >> 16);
}

// global -> LDS direct DMA, 16 B per lane; LDS dest wave-uniform + lane*16.
__device__ __forceinline__ void gload16(const unsigned short* g, unsigned short* l) {
  __builtin_amdgcn_global_load_lds(
      (const __attribute__((address_space(1))) unsigned int*)g,
      (__attribute__((address_space(3))) unsigned int*)l, 16, 0, 0);
}

// Stage one half-tile (128 rows x 64 cols bf16 = 16 KB): 512 thr x 2 x 16 B.
// LDS linear; global source column pre-swizzled (slot j8 <- col j8^(row&7)).
__device__ __forceinline__ void stage_ht(const unsigned short* __restrict__ g,
                                         int Kd, unsigned short* l, int t) {
  const int c0 = t, c1 = t + 512;
  const int r0 = c0 >> 3, r1 = c1 >> 3;
  const int s0 = ((c0 & 7) ^ (r0 & 7)) << 3;
  const int s1 = ((c1 & 7) ^ (r1 & 7)) << 3;
  gload16(g + (size_t)r0 * Kd + s0, l + (c0 << 3));
  gload16(g + (size_t)r1 * Kd + s1, l + (c1 << 3));
}

__global__ void convert_x(const float* __restrict__ src,
                          unsigned short* __restrict__ dst, int n4) {
  int i = blockIdx.x * blockDim.x + threadIdx.x;
  if (i >= n4) return;
  const float4 f = ((const float4*)src)[i];
  ushort4 o;
  o.x = f2bf(f.x); o.y = f2bf(f.y); o.z = f2bf(f.z); o.w = f2bf(f.w);
  ((ushort4*)dst)[i] = o;
}

__global__ void convert_w(const float* __restrict__ s0, const float* __restrict__ s1,
                          const float* __restrict__ s2,
                          unsigned short* __restrict__ d0, unsigned short* __restrict__ d1,
                          unsigned short* __restrict__ d2, int n4) {
  const float* s = (blockIdx.z == 0) ? s0 : (blockIdx.z == 1) ? s1 : s2;
  unsigned short* d = (blockIdx.z == 0) ? d0 : (blockIdx.z == 1) ? d1 : d2;
  int i = blockIdx.x * blockDim.x + threadIdx.x;
  if (i >= n4) return;
  const float4 f = ((const float4*)s)[i];
  ushort4 o;
  o.x = f2bf(f.x); o.y = f2bf(f.y); o.z = f2bf(f.z); o.w = f2bf(f.w);
  ((ushort4*)d)[i] = o;
}

// C[m,n] = sum_k A[m,k]*B[n,k]  (A:[M,K], B:[N,K] bf16 row-major), 256^2 tile.
// LDS layout (halfwords): lds[dbuf*32768 + tensor*16384 + half*8192 + row*64+col]
// per-wave: wrow=w>>2 (2), wcol=w&3 (4); C rows qa*128+wrow*64+s*32, cols
// qb*128+wcol*32. MFMA 32x32x16 maps per m74/m101 (HW-verified).
// MODE 0: bf16 C*alpha; z=1 uses B2/Cout2/alpha2 (QK fusion)
// MODE 1: bf16 exp(C) + atomicAdd per-row exp-sums into rowsum
// MODE 2: split-K over z (kChunk each); atomicAdd fp32 C/rowsum[m] into Cout
template <int MODE>
__launch_bounds__(512, 2)
__global__ void gemm_bt(const unsigned short* __restrict__ A,
                        const unsigned short* __restrict__ B,
                        void* __restrict__ Cout,
                        int M, int N, int K, float alpha,
                        float* __restrict__ rowsum, int kChunk,
                        const unsigned short* __restrict__ B2,
                        void* __restrict__ Cout2, float alpha2) {
  __shared__ __align__(16) unsigned short lds[65536];   // 128 KB

  if (MODE == 0) {
    if (blockIdx.z == 1) { B = B2; Cout = Cout2; alpha = alpha2; }
  }
  const int kOff = (MODE == 2) ? blockIdx.z * kChunk : 0;

  const int t    = threadIdx.x;
  const int w    = t >> 6;
  const int l    = t & 63;
  const int r32  = l & 31;
  const int kh   = l >> 5;
  const int wrow = w >> 2;           // 0..1
  const int wcol = w & 3;            // 0..3
  const int m0   = blockIdx.x * 256;
  const int n0   = blockIdx.y * 256;

  const unsigned short* Ab = A + (size_t)m0 * K + kOff;
  const unsigned short* Bb = B + (size_t)n0 * K + kOff;

  const int arow = wrow * 64 + r32;  // + s*32 -> local row in A-half
  const int brow = wcol * 32 + r32;  // local row in B-half
  const int xr   = (r32 & 7) << 3;
  int cs[4];
#pragma unroll
  for (int ks = 0; ks < 4; ++ks) cs[ks] = (((ks << 1) | kh) << 3) ^ xr;

  f32x16 acc[2][2][2] = {};          // [qa][s][qb]

  const int nt = kChunk >> 6;        // K-tiles (even, >= 4 for all our shapes)
  const int ni = nt >> 1;

#define STG_A(HALF, BUF, JT) stage_ht(Ab + (size_t)((HALF) * 128) * K + (JT) * 64, K, \
                                      &lds[(BUF) * 32768 + (HALF) * 8192], t)
#define STG_B(HALF, BUF, JT) stage_ht(Bb + (size_t)((HALF) * 128) * K + (JT) * 64, K, \
                                      &lds[(BUF) * 32768 + 16384 + (HALF) * 8192], t)
#define RD_A(BUF, QA, DST) do { \
    _Pragma("unroll") for (int s_ = 0; s_ < 2; ++s_) { \
      const int rb_ = (BUF) * 32768 + (QA) * 8192 + (arow + s_ * 32) * 64; \
      _Pragma("unroll") for (int k_ = 0; k_ < 4; ++k_) \
        DST[s_][k_] = *(const bf16x8*)&lds[rb_ + cs[k_]]; \
    } } while (0)
#define RD_B(BUF, QB, DST) do { \
    const int bb_ = (BUF) * 32768 + 16384 + (QB) * 8192 + brow * 64; \
    _Pragma("unroll") for (int k_ = 0; k_ < 4; ++k_) \
      DST[k_] = *(const bf16x8*)&lds[bb_ + cs[k_]]; \
  } while (0)
#define MM8(QA, QB, AA, BB) do { \
    __builtin_amdgcn_s_setprio(1); \
    _Pragma("unroll") for (int k_ = 0; k_ < 4; ++k_) { \
      acc[QA][0][QB] = __builtin_amdgcn_mfma_f32_32x32x16_bf16(AA[0][k_], BB[k_], acc[QA][0][QB], 0, 0, 0); \
      acc[QA][1][QB] = __builtin_amdgcn_mfma_f32_32x32x16_bf16(AA[1][k_], BB[k_], acc[QA][1][QB], 0, 0, 0); \
    } \
    __builtin_amdgcn_s_setprio(0); \
  } while (0)
#define WAITV4() asm volatile("s_waitcnt vmcnt(4)" ::: "memory")
#define WAITV0() asm volatile("s_waitcnt vmcnt(0)" ::: "memory")
#define LGKM0()  asm volatile("s_waitcnt lgkmcnt(0)" ::: "memory")
#define BAR()    __builtin_amdgcn_s_barrier()

  // Prologue: tile0 fully, then tile1.A0 + tile1.B1 (the steady-state
  // "prev ph7/ph8" slots). vmcnt(4) -> tile0's 8 loads landed.
  STG_A(0, 0, 0); STG_B(0, 0, 0); STG_B(1, 0, 0); STG_A(1, 0, 0);
  STG_A(0, 1, 1); STG_B(1, 1, 1);
  WAITV4(); BAR();

  bf16x8 a[2][4], b0[4], b1[4];
  for (int i = 0; i < ni; ++i) {
    const int j = 2 * i;
    const bool full = (i + 1 < ni);
    // ph1: quadrant (0,0) of tile j (dbuf0)
    RD_A(0, 0, a); RD_B(0, 0, b0);
    STG_B(0, 1, j + 1);
    BAR(); LGKM0(); MM8(0, 0, a, b0); BAR();
    // ph2: (0,1) — reuse a0
    RD_B(0, 1, b1);
    STG_A(1, 1, j + 1);
    BAR(); LGKM0(); MM8(0, 1, a, b1); BAR();
    // ph3: (1,1) — reuse b1
    RD_A(0, 1, a);
    if (full) STG_A(0, 0, j + 2);
    BAR(); LGKM0(); MM8(1, 1, a, b1); BAR();
    // ph4: (1,0) — reuse a1, b0; counted wait covers tile j+1 residency
    if (full) { STG_B(1, 0, j + 2); WAITV4(); } else { WAITV0(); }
    BAR(); MM8(1, 0, a, b0); BAR();
    // ph5: quadrant (0,0) of tile j+1 (dbuf1)
    RD_A(1, 0, a); RD_B(1, 0, b0);
    if (full) STG_B(0, 0, j + 2);
    BAR(); LGKM0(); MM8(0, 0, a, b0); BAR();
    // ph6: (0,1)
    RD_B(1, 1, b1);
    if (full) STG_A(1, 0, j + 2);
    BAR(); LGKM0(); MM8(0, 1, a, b1); BAR();
    // ph7: (1,1)
    RD_A(1, 1, a);
    if (full) STG_A(0, 1, j + 3);
    BAR(); LGKM0(); MM8(1, 1, a, b1); BAR();
    // ph8: (1,0); counted wait covers tile j+2 residency for next ph1
    if (full) { STG_B(1, 1, j + 3); WAITV4(); }
    BAR(); MM8(1, 0, a, b0); BAR();
  }

  // C/D 32x32 (m74/m101): col = lane&31, row = (reg&3) + 8*(reg>>2) + 4*kh
  if (MODE == 0) {
    unsigned short* C = (unsigned short*)Cout;
#pragma unroll
    for (int qa = 0; qa < 2; ++qa)
#pragma unroll
      for (int sx = 0; sx < 2; ++sx)
#pragma unroll
        for (int reg = 0; reg < 16; ++reg) {
          const int m = m0 + qa * 128 + wrow * 64 + sx * 32 +
                        (reg & 3) + ((reg >> 2) << 3) + (kh << 2);
#pragma unroll
          for (int qb = 0; qb < 2; ++qb) {
            const int n = n0 + qb * 128 + wcol * 32 + r32;
            C[(size_t)m * N + n] = f2bf(acc[qa][sx][qb][reg] * alpha);
          }
        }
  } else if (MODE == 1) {
    unsigned short* C = (unsigned short*)Cout;
#pragma unroll
    for (int qa = 0; qa < 2; ++qa)
#pragma unroll
      for (int sx = 0; sx < 2; ++sx)
#pragma unroll
        for (int reg = 0; reg < 16; ++reg) {
          const int m = m0 + qa * 128 + wrow * 64 + sx * 32 +
                        (reg & 3) + ((reg >> 2) << 3) + (kh << 2);
          float sum = 0.f;
#pragma unroll
          for (int qb = 0; qb < 2; ++qb) {
            const int n = n0 + qb * 128 + wcol * 32 + r32;
            float p = __expf(acc[qa][sx][qb][reg]);
            C[(size_t)m * N + n] = f2bf(p);
            sum += p;
          }
          // reduce over the 32 lanes (r32) sharing this row
#pragma unroll
          for (int off = 1; off < 32; off <<= 1) sum += __shfl_xor(sum, off, 64);
          if (r32 == 0) atomicAdd(&rowsum[m], sum);
        }
  } else {
    float* C = (float*)Cout;   // fp32, zero-initialized; split-K partials
#pragma unroll
    for (int qa = 0; qa < 2; ++qa)
#pragma unroll
      for (int sx = 0; sx < 2; ++sx)
#pragma unroll
        for (int reg = 0; reg < 16; ++reg) {
          const int m = m0 + qa * 128 + wrow * 64 + sx * 32 +
                        (reg & 3) + ((reg >> 2) << 3) + (kh << 2);
          const float inv = 1.0f / rowsum[m];
#pragma unroll
          for (int qb = 0; qb < 2; ++qb) {
            const int n = n0 + qb * 128 + wcol * 32 + r32;
            atomicAdd(&C[(size_t)m * N + n], acc[qa][sx][qb][reg] * inv);
          }
        }
  }
#undef STG_A
#undef STG_B
#undef RD_A
#undef RD_B
#undef MM8
#undef WAITV4
#undef WAITV0
#undef LGKM0
#undef BAR
}

extern "C" void kernel_launch(void* const* d_in, const int* in_sizes, int n_in,
                              void* d_out, int out_size, void* d_ws, size_t ws_size,
                              hipStream_t stream) {
  const float* x  = (const float*)d_in[0];
  const float* Wq = (const float*)d_in[1];
  const float* Wk = (const float*)d_in[2];
  const float* Wv = (const float*)d_in[3];

  char* ws = (char*)d_ws;
  unsigned short* xb     = (unsigned short*)(ws + 0);
  unsigned short* Qb     = (unsigned short*)(ws + 12582912);
  unsigned short* Kb     = (unsigned short*)(ws + 25165824);
  unsigned short* Vtb    = (unsigned short*)(ws + 37748736);
  unsigned short* wqb    = (unsigned short*)(ws + 50331648);
  unsigned short* wkb    = (unsigned short*)(ws + 51511296);
  unsigned short* wvb    = (unsigned short*)(ws + 52690944);
  float*          rowsum = (float*)(ws + 53870592);
  unsigned short* Pb     = (unsigned short*)(ws + 53903360);
  const size_t need = 53903360u + (size_t)SEQ * SEQ * 2u;
  if (ws_size < need) return;

  hipMemsetAsync(rowsum, 0, SEQ * sizeof(float), stream);
  hipMemsetAsync(d_out, 0, (size_t)out_size * sizeof(float), stream);

  convert_x<<<SEQ * DMODEL / 1024, 256, 0, stream>>>(x, xb, SEQ * DMODEL / 4);
  convert_w<<<dim3(DMODEL * DMODEL / 1024, 1, 3), 256, 0, stream>>>(
      Wq, Wk, Wv, wqb, wkb, wvb, DMODEL * DMODEL / 4);

  const float alpha_q = 0.03608439182435161f;  // 1/sqrt(768)
  dim3 blk(512);
  // 256^2 tiles: grid.x = M-tiles, grid.y = N-tiles
  gemm_bt<0><<<dim3(SEQ / 256, DMODEL / 256, 2), blk, 0, stream>>>(
      xb, wqb, Qb, SEQ, DMODEL, DMODEL, alpha_q, nullptr, DMODEL,
      wkb, Kb, 1.0f);
  gemm_bt<0><<<dim3(DMODEL / 256, SEQ / 256, 1), blk, 0, stream>>>(
      wvb, xb, Vtb, DMODEL, SEQ, DMODEL, 1.0f, nullptr, DMODEL,
      nullptr, nullptr, 1.0f);
  gemm_bt<1><<<dim3(SEQ / 256, SEQ / 256, 1), blk, 0, stream>>>(
      Qb, Kb, Pb, SEQ, SEQ, DMODEL, 1.0f, rowsum, DMODEL,
      nullptr, nullptr, 1.0f);
  gemm_bt<2><<<dim3(SEQ / 256, DMODEL / 256, KSPLIT), blk, 0, stream>>>(
      Pb, Vtb, d_out, SEQ, DMODEL, SEQ, 1.0f, rowsum, SEQ / KSPLIT,
      nullptr, nullptr, 1.0f);
}

// Round 7
// 391.892 us; speedup vs baseline: 1.7189x; 1.7189x over previous
//
#include <hip/hip_runtime.h>
#include <stdint.h>

// Self-attention, SEQ=8192, D=768, single head.
//   K0a: x fp32->bf16; K0b: Wq/Wk/Wv fp32->bf16 (z-fused)
//   K1a: Q,K projections z-fused (128^2 engine, MODE 0)
//   K1b: Vt = Wv x^T (128^2, MODE 0)
//   K2 : P' = exp(Q K^T) bf16 + atomic row sums  -> NEW 256^2 8-phase engine
//   K3 : out += (P'_chunk V)/rowsum, split-K x4 (128^2, MODE 2)
//
// R17: R16 post-mortem found the 8-phase port broke three m201 invariants:
//   (1) 32x32x16 quadrant-phases -> only 2 acc chains (dist 2) per phase;
//       16x16x32 gives 8 chains (dist 8). Shape is load-bearing.
//   (2) vmcnt(4)=2 half-tiles in flight (min 2-phase flight ~600cyc < miss
//       latency); correct is vmcnt(6)=3 half-tiles, min 3-phase flight.
//   (3) b-frags re-read instead of register-held -> wrong read/stage windows.
// Derived schedule (reads-once-into-regs, (qa,b-half) phases):
//   ph1: rd a(qa0)8+b0 4, stage d1.A1(j+1);  ph2: rd b1 4, stage d0.A0(j+2)
//   ph3: rd a(qa1)8      , stage d0.B0(j+2);  ph4: rd 0,   stage d0.B1(j+2)
//   ph5-8 mirror on d1 (stages: d0.A1(j+2), d1.A0/B0/B1(j+3))
//   WAITV(6) after MM at ph4 & ph8. Slot algebra: entering ph1 in-flight =
//   {A0,B0,B1}(j+1); ph4-wait completes those + ph1's A1(j+1) (flight>=3);
//   ph8-wait completes tile j+2's 4 halves. Region liveness: every staged
//   region's last ds_read is >=1 barrier before the stage issue.
// K2 only (1024 blocks = 4/CU-serial); small/odd-shaped GEMMs stay on the
// measured R15 128^2 engine (K3 port follows if K2 proves out).

#define SEQ    8192
#define DMODEL 768
#define KSPLIT 4
#define LROW   64            // 128^2 engine LDS row stride (halfwords)

typedef short bf16x8 __attribute__((ext_vector_type(8)));
typedef float f32x4  __attribute__((ext_vector_type(4)));
typedef float f32x16 __attribute__((ext_vector_type(16)));

__device__ __forceinline__ unsigned short f2bf(float f) {
  union { float f; unsigned int u; } v; v.f = f;
  unsigned int u = v.u;
  u += 0x7FFFu + ((u >> 16) & 1u);   // round-to-nearest-even
  return (unsigned short)(u >> 16);
}

// global -> LDS direct DMA, 16 B/lane; LDS dest wave-uniform + lane*16 (m104).
__device__ __forceinline__ void gload16(const unsigned short* g, unsigned short* l) {
  __builtin_amdgcn_global_load_lds(
      (const __attribute__((address_space(1))) unsigned int*)g,
      (__attribute__((address_space(3))) unsigned int*)l, 16, 0, 0);
}

// Stage one half-tile (128x64 bf16 = 16 KB): 512 thr x 2 x 16 B.
// LDS linear; source column pre-swizzled (slot j <- col j^(row&7)).
__device__ __forceinline__ void stage_ht(const unsigned short* __restrict__ g,
                                         int Kd, unsigned short* l, int t) {
  const int c0 = t, c1 = t + 512;
  const int r0 = c0 >> 3, r1 = c1 >> 3;
  const int s0 = ((c0 & 7) ^ (r0 & 7)) << 3;
  const int s1 = ((c1 & 7) ^ (r1 & 7)) << 3;
  gload16(g + (size_t)r0 * Kd + s0, l + (c0 << 3));
  gload16(g + (size_t)r1 * Kd + s1, l + (c1 << 3));
}

__global__ void convert_x(const float* __restrict__ src,
                          unsigned short* __restrict__ dst, int n4) {
  int i = blockIdx.x * blockDim.x + threadIdx.x;
  if (i >= n4) return;
  const float4 f = ((const float4*)src)[i];
  ushort4 o;
  o.x = f2bf(f.x); o.y = f2bf(f.y); o.z = f2bf(f.z); o.w = f2bf(f.w);
  ((ushort4*)dst)[i] = o;
}

__global__ void convert_w(const float* __restrict__ s0, const float* __restrict__ s1,
                          const float* __restrict__ s2,
                          unsigned short* __restrict__ d0, unsigned short* __restrict__ d1,
                          unsigned short* __restrict__ d2, int n4) {
  const float* s = (blockIdx.z == 0) ? s0 : (blockIdx.z == 1) ? s1 : s2;
  unsigned short* d = (blockIdx.z == 0) ? d0 : (blockIdx.z == 1) ? d1 : d2;
  int i = blockIdx.x * blockDim.x + threadIdx.x;
  if (i >= n4) return;
  const float4 f = ((const float4*)s)[i];
  ushort4 o;
  o.x = f2bf(f.x); o.y = f2bf(f.y); o.z = f2bf(f.z); o.w = f2bf(f.w);
  ((ushort4*)d)[i] = o;
}

// ---------------- 256^2 8-phase engine (K2 only) ----------------
// C[m,n]=sum_k A[m,k]B[n,k]; writes exp(C) bf16 + atomic rowsums.
// 8 waves (2M x 4N); per-wave out = rows {qa*128+wrow*64+0..63} x cols
// {bh*128+wcol*32+0..31} (2x2 of 64x32). MFMA 16x16x32: A/B frag lane
// row=l&15, k=(l>>4)*8+j; C/D col=l&15, row=(l>>4)*4+reg [m89/m91].
// LDS halfwords: [dbuf2][tensor2][half2][128][64]=65536 (128 KB).
__launch_bounds__(512, 2)
__global__ void gemm256_exp(const unsigned short* __restrict__ A,
                            const unsigned short* __restrict__ B,
                            unsigned short* __restrict__ C,
                            int N, int K, float* __restrict__ rowsum) {
  __shared__ __align__(16) unsigned short lds[65536];
  const int t    = threadIdx.x;
  const int w    = t >> 6, l = t & 63;
  const int lr   = l & 15, lq = l >> 4;
  const int wrow = w >> 2, wcol = w & 3;
  const int m0   = blockIdx.x * 256;
  const int n0   = blockIdx.y * 256;
  const unsigned short* Ab = A + (size_t)m0 * K;
  const unsigned short* Bb = B + (size_t)n0 * K;

  // hoisted read-address pieces: row_local*64 and swizzled k-chunk offsets
  const int rA64 = (wrow * 64 + lr) * 64;
  const int rB64 = (wcol * 32 + lr) * 64;
  const int x7   = lr & 7;
  const int csw0 = ((0 + lq) ^ x7) << 3;   // ks=0 chunk
  const int csw1 = ((4 + lq) ^ x7) << 3;   // ks=1 chunk

  f32x4 acc[2][2][4][2] = {};              // [qa][bh][rt][ct]
  const int nt = K >> 6, ni = nt >> 1;     // K-tiles (even for all our K)

#define STG(T, H, D, JT) stage_ht(((T) ? Bb : Ab) + (size_t)((H) * 128) * K + (JT) * 64, K, \
                                  &lds[(D) * 32768 + (T) * 16384 + (H) * 8192], t)
#define RDA(D, QA) do { \
    _Pragma("unroll") for (int rt = 0; rt < 4; ++rt) { \
      a[rt][0] = *(const bf16x8*)&lds[(D)*32768 + (QA)*8192 + rA64 + rt*1024 + csw0]; \
      a[rt][1] = *(const bf16x8*)&lds[(D)*32768 + (QA)*8192 + rA64 + rt*1024 + csw1]; \
    } } while (0)
#define RDB(D, BH, DST) do { \
    _Pragma("unroll") for (int ct = 0; ct < 2; ++ct) { \
      DST[ct][0] = *(const bf16x8*)&lds[(D)*32768 + 16384 + (BH)*8192 + rB64 + ct*1024 + csw0]; \
      DST[ct][1] = *(const bf16x8*)&lds[(D)*32768 + 16384 + (BH)*8192 + rB64 + ct*1024 + csw1]; \
    } } while (0)
#define MM16(QA, BH, BR) do { \
    __builtin_amdgcn_s_setprio(1); \
    _Pragma("unroll") for (int ks = 0; ks < 2; ++ks) \
      _Pragma("unroll") for (int rt = 0; rt < 4; ++rt) \
        _Pragma("unroll") for (int ct = 0; ct < 2; ++ct) \
          acc[QA][BH][rt][ct] = __builtin_amdgcn_mfma_f32_16x16x32_bf16( \
              a[rt][ks], BR[ct][ks], acc[QA][BH][rt][ct], 0, 0, 0); \
    __builtin_amdgcn_s_setprio(0); \
  } while (0)
#define WAITV6() asm volatile("s_waitcnt vmcnt(6)" ::: "memory")
#define WAITV0() asm volatile("s_waitcnt vmcnt(0)" ::: "memory")
#define LGKM0()  asm volatile("s_waitcnt lgkmcnt(0)" ::: "memory")
#define BAR()    __builtin_amdgcn_s_barrier()

  bf16x8 a[4][2], b0[2][2], b1[2][2];

  // Prologue: tile0 (A0,B0,B1,A1)->d0, tile1 (A0,B0,B1)->d1; 7 slots,
  // drain to 3 -> tile0 resident, {A0,B0,B1}(1) in flight = loop invariant.
  STG(0, 0, 0, 0); STG(1, 0, 0, 0); STG(1, 1, 0, 0); STG(0, 1, 0, 0);
  STG(0, 0, 1, 1); STG(1, 0, 1, 1); STG(1, 1, 1, 1);
  WAITV6(); BAR();

  for (int i = 0; i < ni; ++i) {
    const int j = 2 * i;
    const bool full = (i + 1 < ni);
    // ph1 (d0, qa0, b0): 12 reads; stage d1.A1(j+1)
    RDA(0, 0); RDB(0, 0, b0); STG(0, 1, 1, j + 1);
    BAR(); LGKM0(); MM16(0, 0, b0); BAR();
    // ph2 (d0, qa0, b1): 4 reads; stage d0.A0(j+2) [d0.A0 read only ph1]
    RDB(0, 1, b1); if (full) STG(0, 0, 0, j + 2);
    BAR(); LGKM0(); MM16(0, 1, b1); BAR();
    // ph3 (d0, qa1, b0): 8 reads (b0 held from ph1); stage d0.B0(j+2)
    RDA(0, 1); if (full) STG(1, 0, 0, j + 2);
    BAR(); LGKM0(); MM16(1, 0, b0); BAR();
    // ph4 (d0, qa1, b1): 0 reads (a ph3, b1 ph2); stage d0.B1(j+2);
    // counted wait AFTER MFMA -> tile j+1 resident for ph5
    if (full) STG(1, 1, 0, j + 2);
    BAR(); MM16(1, 1, b1);
    if (full) { WAITV6(); } else { WAITV0(); }
    BAR();
    // ph5 (d1, qa0, b0): 12 reads; stage d0.A1(j+2) [d0.A1 read ph3]
    RDA(1, 0); RDB(1, 0, b0); if (full) STG(0, 1, 0, j + 2);
    BAR(); LGKM0(); MM16(0, 0, b0); BAR();
    // ph6 (d1, qa0, b1): 4 reads; stage d1.A0(j+3) [d1.A0 read ph5]
    RDB(1, 1, b1); if (full) STG(0, 0, 1, j + 3);
    BAR(); LGKM0(); MM16(0, 1, b1); BAR();
    // ph7 (d1, qa1, b0): 8 reads; stage d1.B0(j+3)
    RDA(1, 1); if (full) STG(1, 0, 1, j + 3);
    BAR(); LGKM0(); MM16(1, 0, b0); BAR();
    // ph8 (d1, qa1, b1): 0 reads; stage d1.B1(j+3); counted wait -> tile
    // j+2 resident for next ph1
    if (full) STG(1, 1, 1, j + 3);
    BAR(); MM16(1, 1, b1);
    if (full) WAITV6();
    BAR();
  }

  // Epilogue: exp + bf16 store + per-row exp-sum (16-lane groups share m).
#pragma unroll
  for (int qa = 0; qa < 2; ++qa)
#pragma unroll
    for (int rt = 0; rt < 4; ++rt)
#pragma unroll
      for (int reg = 0; reg < 4; ++reg) {
        const int m = m0 + qa * 128 + wrow * 64 + rt * 16 + lq * 4 + reg;
        float s = 0.f;
#pragma unroll
        for (int bh = 0; bh < 2; ++bh)
#pragma unroll
          for (int ct = 0; ct < 2; ++ct) {
            const int n = n0 + bh * 128 + wcol * 32 + ct * 16 + lr;
            float p = __expf(acc[qa][bh][rt][ct][reg]);
            C[(size_t)m * N + n] = f2bf(p);
            s += p;
          }
#pragma unroll
        for (int off = 1; off < 16; off <<= 1) s += __shfl_xor(s, off, 64);
        if (lr == 0) atomicAdd(&rowsum[m], s);
      }
#undef STG
#undef RDA
#undef RDB
#undef MM16
#undef WAITV6
#undef WAITV0
#undef LGKM0
#undef BAR
}

// ---------------- 128^2 2-barrier engine (R15, measured 427 total) ----------
template <int MODE>
__launch_bounds__(256, 4)
__global__ void gemm_bt(const unsigned short* __restrict__ A,
                        const unsigned short* __restrict__ B,
                        void* __restrict__ Cout,
                        int M, int N, int K, float alpha,
                        float* __restrict__ rowsum, int kChunk,
                        const unsigned short* __restrict__ B2,
                        void* __restrict__ Cout2, float alpha2) {
  __shared__ __align__(16) unsigned short lA[128 * LROW];
  __shared__ __align__(16) unsigned short lB[128 * LROW];

  if (MODE == 0) {
    if (blockIdx.z == 1) { B = B2; Cout = Cout2; alpha = alpha2; }
  }
  const int kOff = (MODE == 2) ? blockIdx.z * kChunk : 0;

  const int t    = threadIdx.x;
  const int w    = t >> 6;
  const int l    = t & 63;
  const int r32  = l & 31;
  const int kh   = l >> 5;
  const int m0   = blockIdx.x * 128;
  const int n0   = blockIdx.y * 128;
  const int wm   = (w & 1) * 64;
  const int wn   = (w >> 1) * 64;

  int gOff[4], dOff[4];
#pragma unroll
  for (int h = 0; h < 4; ++h) {
    int c   = t + (h << 8);
    int row = c >> 3;
    int j   = c & 7;
    gOff[h] = row * K + ((j ^ (row & 7)) << 3);
    dOff[h] = c << 3;
  }
  const unsigned short* Abase = A + (size_t)m0 * K + kOff;
  const unsigned short* Bbase = B + (size_t)n0 * K + kOff;

  const int xr = (r32 & 7) << 3;
  int offA0[4], offA1[4], offB0[4], offB1[4];
#pragma unroll
  for (int ks = 0; ks < 4; ++ks) {
    const int gg = (((ks << 1) | kh) << 3) ^ xr;
    offA0[ks] = (wm      + r32) * LROW + gg;
    offA1[ks] = (wm + 32 + r32) * LROW + gg;
    offB0[ks] = (wn      + r32) * LROW + gg;
    offB1[ks] = (wn + 32 + r32) * LROW + gg;
  }

  f32x16 acc[2][2] = {};
  const int nk = kChunk >> 6;

#pragma unroll
  for (int h = 0; h < 4; ++h) gload16(Abase + gOff[h], &lA[dOff[h]]);
#pragma unroll
  for (int h = 0; h < 4; ++h) gload16(Bbase + gOff[h], &lB[dOff[h]]);
  __syncthreads();

  for (int kt = 0; kt < nk; ++kt) {
#pragma unroll
    for (int ks = 0; ks < 4; ++ks) {
      bf16x8 a0 = *(const bf16x8*)&lA[offA0[ks]];
      bf16x8 a1 = *(const bf16x8*)&lA[offA1[ks]];
      bf16x8 b0 = *(const bf16x8*)&lB[offB0[ks]];
      bf16x8 b1 = *(const bf16x8*)&lB[offB1[ks]];
      acc[0][0] = __builtin_amdgcn_mfma_f32_32x32x16_bf16(a0, b0, acc[0][0], 0, 0, 0);
      acc[0][1] = __builtin_amdgcn_mfma_f32_32x32x16_bf16(a0, b1, acc[0][1], 0, 0, 0);
      acc[1][0] = __builtin_amdgcn_mfma_f32_32x32x16_bf16(a1, b0, acc[1][0], 0, 0, 0);
      acc[1][1] = __builtin_amdgcn_mfma_f32_32x32x16_bf16(a1, b1, acc[1][1], 0, 0, 0);
    }
    if (kt + 1 < nk) {
      __syncthreads();
      const int ko = (kt + 1) << 6;
#pragma unroll
      for (int h = 0; h < 4; ++h) gload16(Abase + gOff[h] + ko, &lA[dOff[h]]);
#pragma unroll
      for (int h = 0; h < 4; ++h) gload16(Bbase + gOff[h] + ko, &lB[dOff[h]]);
      __syncthreads();
    }
  }

  if (MODE == 0) {
    unsigned short* C = (unsigned short*)Cout;
#pragma unroll
    for (int mi = 0; mi < 2; ++mi)
#pragma unroll
      for (int reg = 0; reg < 16; ++reg) {
        int m = m0 + wm + mi * 32 + (reg & 3) + ((reg >> 2) << 3) + (kh << 2);
#pragma unroll
        for (int ni = 0; ni < 2; ++ni) {
          int n = n0 + wn + ni * 32 + r32;
          C[(size_t)m * N + n] = f2bf(acc[mi][ni][reg] * alpha);
        }
      }
  } else if (MODE == 1) {
    unsigned short* C = (unsigned short*)Cout;
#pragma unroll
    for (int mi = 0; mi < 2; ++mi)
#pragma unroll
      for (int reg = 0; reg < 16; ++reg) {
        int m = m0 + wm + mi * 32 + (reg & 3) + ((reg >> 2) << 3) + (kh << 2);
        float s = 0.f;
#pragma unroll
        for (int ni = 0; ni < 2; ++ni) {
          int n = n0 + wn + ni * 32 + r32;
          float p = __expf(acc[mi][ni][reg]);
          C[(size_t)m * N + n] = f2bf(p);
          s += p;
        }
#pragma unroll
        for (int off = 1; off < 32; off <<= 1) s += __shfl_xor(s, off, 64);
        if (r32 == 0) atomicAdd(&rowsum[m], s);
      }
  } else {
    float* C = (float*)Cout;
#pragma unroll
    for (int mi = 0; mi < 2; ++mi)
#pragma unroll
      for (int reg = 0; reg < 16; ++reg) {
        int m = m0 + wm + mi * 32 + (reg & 3) + ((reg >> 2) << 3) + (kh << 2);
        float inv = 1.0f / rowsum[m];
#pragma unroll
        for (int ni = 0; ni < 2; ++ni) {
          int n = n0 + wn + ni * 32 + r32;
          atomicAdd(&C[(size_t)m * N + n], acc[mi][ni][reg] * inv);
        }
      }
  }
}

extern "C" void kernel_launch(void* const* d_in, const int* in_sizes, int n_in,
                              void* d_out, int out_size, void* d_ws, size_t ws_size,
                              hipStream_t stream) {
  const float* x  = (const float*)d_in[0];
  const float* Wq = (const float*)d_in[1];
  const float* Wk = (const float*)d_in[2];
  const float* Wv = (const float*)d_in[3];

  char* ws = (char*)d_ws;
  unsigned short* xb     = (unsigned short*)(ws + 0);
  unsigned short* Qb     = (unsigned short*)(ws + 12582912);
  unsigned short* Kb     = (unsigned short*)(ws + 25165824);
  unsigned short* Vtb    = (unsigned short*)(ws + 37748736);
  unsigned short* wqb    = (unsigned short*)(ws + 50331648);
  unsigned short* wkb    = (unsigned short*)(ws + 51511296);
  unsigned short* wvb    = (unsigned short*)(ws + 52690944);
  float*          rowsum = (float*)(ws + 53870592);
  unsigned short* Pb     = (unsigned short*)(ws + 53903360);
  const size_t need = 53903360u + (size_t)SEQ * SEQ * 2u;
  if (ws_size < need) return;

  hipMemsetAsync(rowsum, 0, SEQ * sizeof(float), stream);
  hipMemsetAsync(d_out, 0, (size_t)out_size * sizeof(float), stream);

  convert_x<<<SEQ * DMODEL / 1024, 256, 0, stream>>>(x, xb, SEQ * DMODEL / 4);
  convert_w<<<dim3(DMODEL * DMODEL / 1024, 1, 3), 256, 0, stream>>>(
      Wq, Wk, Wv, wqb, wkb, wvb, DMODEL * DMODEL / 4);

  const float alpha_q = 0.03608439182435161f;  // 1/sqrt(768)
  // K1a/K1b on the 128^2 engine (good block counts: 768 / 384 blocks)
  gemm_bt<0><<<dim3(SEQ / 128, DMODEL / 128, 2), dim3(256), 0, stream>>>(
      xb, wqb, Qb, SEQ, DMODEL, DMODEL, alpha_q, nullptr, DMODEL,
      wkb, Kb, 1.0f);
  gemm_bt<0><<<dim3(DMODEL / 128, SEQ / 128, 1), dim3(256), 0, stream>>>(
      wvb, xb, Vtb, DMODEL, SEQ, DMODEL, 1.0f, nullptr, DMODEL,
      nullptr, nullptr, 1.0f);
  // K2 on the 256^2 8-phase engine (1024 blocks)
  gemm256_exp<<<dim3(SEQ / 256, SEQ / 256), dim3(512), 0, stream>>>(
      Qb, Kb, Pb, SEQ, DMODEL, rowsum);
  // K3 on the 128^2 engine, split-K x4
  gemm_bt<2><<<dim3(SEQ / 128, DMODEL / 128, KSPLIT), dim3(256), 0, stream>>>(
      Pb, Vtb, d_out, SEQ, DMODEL, SEQ, 1.0f, rowsum, SEQ / KSPLIT,
      nullptr, nullptr, 1.0f);
}